// Round 7
// baseline (484.496 us; speedup 1.0000x reference)
//
#include <hip/hip_runtime.h>
#include <cstdint>
#include <cstddef>

// VAE forward, fused bf16-MFMA pipeline.
// Sizes fixed: B=32768, INPUT=1024, HIDDEN=1024, LATENT=128.
//
// R7: GEMM3 fused into gemm2_zkl -> gemm23_zkl. Phase 1 computes the
//     encoder heads (h @ [Wmu|Wls]) per 64-row block; epilogue-1 forms
//     z = mu+exp(ls)*eps IN REGISTERS and writes it to LDS (swizzled
//     A-operand layout) instead of global; phase 2 loops 8 col-chunks of
//     wd1t (128x128 staged per chunk) computing hd = relu(z@Wd1+bd1).
//     Removes: GEMM3 launch+gap, 16MB z round-trip, z buffer, and GEMM3's
//     per-block fixed overhead (K=128 made it prologue-dominated).
// R6 (kept): gemm_bt at 128x128/BK=64 (confirmed local optimum; R5's
//     fatter tile halved occupancy and regressed).
// R5 (kept): fused prep kernel (5 transposes + x cast).
// R3 (kept): XCD-pinned 1D grid decode (FETCH 298->90MB).
// R2 (kept): XOR-swizzled staging (LDS bank conflicts -> 0).

typedef __bf16 bf16x8 __attribute__((ext_vector_type(8)));
typedef float f32x4 __attribute__((ext_vector_type(4)));

__device__ __forceinline__ unsigned short f32_to_bf16(float f) {
  unsigned int u = __float_as_uint(f);
  u += 0x7fffu + ((u >> 16) & 1u);   // round-to-nearest-even (finite values)
  return (unsigned short)(u >> 16);
}

// ------------- fused prep: 5 transposes + x-cast in one kernel -------------
struct TransJob { const float* in; unsigned short* out; int K, N, blkEnd; };

__global__ void prep_k(TransJob j0, TransJob j1, TransJob j2, TransJob j3,
                       TransJob j4, const float* __restrict__ x,
                       unsigned short* __restrict__ xbf, int n4) {
  int bid = blockIdx.x;
  int tid = threadIdx.y * 32 + threadIdx.x;
  if (bid >= 2432) {
    int base = (bid - 2432) * 256 + tid;
    int stride = 2048 * 256;
#pragma unroll
    for (int it = 0; it < 16; ++it) {
      int i = base + it * stride;
      float4 v = reinterpret_cast<const float4*>(x)[i];
      ushort4 o = make_ushort4(f32_to_bf16(v.x), f32_to_bf16(v.y),
                               f32_to_bf16(v.z), f32_to_bf16(v.w));
      reinterpret_cast<ushort4*>(xbf)[i] = o;
    }
    return;
  }
  __shared__ float tile[32][33];
  TransJob j; int base;
  if (bid < j0.blkEnd)      { j = j0; base = 0; }
  else if (bid < j1.blkEnd) { j = j1; base = j0.blkEnd; }
  else if (bid < j2.blkEnd) { j = j2; base = j1.blkEnd; }
  else if (bid < j3.blkEnd) { j = j3; base = j2.blkEnd; }
  else                      { j = j4; base = j3.blkEnd; }
  int local = bid - base;
  int gxN = j.N >> 5;
  int n0 = (local % gxN) * 32, k0 = (local / gxN) * 32;
  int tx = threadIdx.x, ty = threadIdx.y;  // block is 32x8
#pragma unroll
  for (int r = 0; r < 32; r += 8)
    tile[ty + r][tx] = j.in[(size_t)(k0 + ty + r) * j.N + n0 + tx];
  __syncthreads();
#pragma unroll
  for (int r = 0; r < 32; r += 8)
    j.out[(size_t)(n0 + ty + r) * j.K + k0 + tx] = f32_to_bf16(tile[tx][ty + r]);
}

// async global->LDS, 16B per lane; LDS dest must be contiguous in lane order
__device__ __forceinline__ void gl_lds16(const unsigned short* g, unsigned short* l) {
  __builtin_amdgcn_global_load_lds(
      (__attribute__((address_space(1))) void*)g,
      (__attribute__((address_space(3))) void*)l, 16, 0, 0);
}

// ---------------- GEMM: C = A[M][K] @ BT[N][K]^T + bias, 128x128 tile, BK=64 ----------------
// 1D grid, XCD-pinned decode. EPI 0: relu->bf16. EPI 2: bernoulli LL rowsum atomicAdd.
template <int EPI>
__global__ __launch_bounds__(256) void gemm_bt(
    const unsigned short* __restrict__ A, const unsigned short* __restrict__ BT,
    int gx, int N, int K,
    const float* __restrict__ bias0,
    unsigned short* __restrict__ outb, float* __restrict__ outf,
    const unsigned short* __restrict__ xbf) {
  __shared__ __align__(16) unsigned short As[128 * 64];   // 16 KB
  __shared__ __align__(16) unsigned short Bs[128 * 64];   // 16 KB

  const int tid = threadIdx.x;
  const int lane = tid & 63;
  const int wave = tid >> 6;
  const int wr = wave >> 1, wc = wave & 1;   // 64x64 quadrant
  const int bid = blockIdx.x;
  const int xcd = bid & 7;
  const int t8 = bid >> 3;
  const int m0 = (xcd + 8 * (t8 / gx)) * 128;
  const int n0 = (t8 % gx) * 128;
  const int lm = lane & 15, lq = lane >> 4;

  // staging: 1024 16B-chunks per tile -> 4 per thread; chunk c: row=c>>3,
  // LDS slot c&7 holds global chunk (c&7)^(row&7)
  const unsigned short* agp[4];
  const unsigned short* bgp[4];
#pragma unroll
  for (int r = 0; r < 4; ++r) {
    int c = tid + 256 * r;
    int row = c >> 3, q = (c & 7) ^ (row & 7);
    agp[r] = A + (size_t)(m0 + row) * K + q * 8;
    bgp[r] = BT + (size_t)(n0 + row) * K + q * 8;
  }
  const int sw = lm & 7;   // read-side swizzle

  f32x4 acc[4][4] = {};

  for (int kt = 0; kt < K; kt += 64) {
#pragma unroll
    for (int r = 0; r < 4; ++r) {
      gl_lds16(agp[r] + kt, As + (tid + 256 * r) * 8);
      gl_lds16(bgp[r] + kt, Bs + (tid + 256 * r) * 8);
    }
    __syncthreads();

#pragma unroll
    for (int s = 0; s < 2; ++s) {
      const int so = ((s << 2) | lq) ^ sw;
      bf16x8 af[4], bfr[4];
#pragma unroll
      for (int i = 0; i < 4; ++i)
        af[i] = *reinterpret_cast<const bf16x8*>(As + (wr * 64 + i * 16 + lm) * 64 + so * 8);
#pragma unroll
      for (int j = 0; j < 4; ++j)
        bfr[j] = *reinterpret_cast<const bf16x8*>(Bs + (wc * 64 + j * 16 + lm) * 64 + so * 8);
#pragma unroll
      for (int i = 0; i < 4; ++i)
#pragma unroll
        for (int j = 0; j < 4; ++j)
          acc[i][j] = __builtin_amdgcn_mfma_f32_16x16x32_bf16(af[i], bfr[j], acc[i][j], 0, 0, 0);
    }
    __syncthreads();
  }

  if (EPI == 0) {
#pragma unroll
    for (int i = 0; i < 4; ++i)
#pragma unroll
      for (int j = 0; j < 4; ++j) {
        int col = n0 + wc * 64 + j * 16 + lm;
        float bias = bias0[col];
#pragma unroll
        for (int r = 0; r < 4; ++r) {
          int row = m0 + wr * 64 + i * 16 + lq * 4 + r;
          float v = acc[i][j][r] + bias;
          v = fmaxf(v, 0.f);
          outb[(size_t)row * N + col] = f32_to_bf16(v);
        }
      }
  } else {
#pragma unroll
    for (int i = 0; i < 4; ++i) {
      float rs[4] = {0.f, 0.f, 0.f, 0.f};
#pragma unroll
      for (int j = 0; j < 4; ++j) {
        int col = n0 + wc * 64 + j * 16 + lm;
        float bias = bias0[col];
#pragma unroll
        for (int r = 0; r < 4; ++r) {
          int row = m0 + wr * 64 + i * 16 + lq * 4 + r;
          float l = acc[i][j][r] + bias;
          unsigned short xb = xbf[(size_t)row * N + col];  // 0x0000 or 0x3F80
          float t = xb ? -l : l;
          float sp = fmaxf(t, 0.f) + __logf(1.f + __expf(-fabsf(t)));
          rs[r] -= sp;
        }
      }
#pragma unroll
      for (int off = 1; off < 16; off <<= 1)
#pragma unroll
        for (int r = 0; r < 4; ++r) rs[r] += __shfl_xor(rs[r], off, 64);
      if (lm == 0) {
#pragma unroll
        for (int r = 0; r < 4; ++r)
          atomicAdd(&outf[m0 + wr * 64 + i * 16 + lq * 4 + r], rs[r]);
      }
    }
  }
}

// -------- gemm23_zkl: encoder heads + z/kl + decoder layer 1, one kernel --------
// Phase 1: 64x256 tile (4 waves x 16 rows x 256 cols), BK=64, K=1024:
//   S2 = h @ w2t^T; acc[j]: mu at n-tile j (j<8), ls at j+8 (same lane).
// Epilogue-1: z = mu+exp(ls)*eps -> LDS zs[64][128] (8-elem chunks XOR-swizzled
//   by row&15); kl rowsum -> out[b] = -kl[b].
// Phase 2: hd = relu(z @ Wd1 + bd1) over 8 col-chunks of wd1t (128 N x 128 K
//   staged per chunk); wave w computes 64 rows x cols [w*32, w*32+32).
__global__ __launch_bounds__(256) void gemm23_zkl(
    const unsigned short* __restrict__ A,     // h [B][1024]
    const unsigned short* __restrict__ BT,    // w2t [256][1024]
    const unsigned short* __restrict__ WD1,   // wd1t [1024][128]
    const float* __restrict__ bmu, const float* __restrict__ bls,
    const float* __restrict__ bd1,
    const float* __restrict__ eps,            // [B][128]
    unsigned short* __restrict__ hd,          // [B][1024] (may alias A: same rows)
    float* __restrict__ out) {
  __shared__ __align__(16) unsigned short lds[24576];  // 48 KB
  unsigned short* As = lds;           // phase1 A: 64x64   (shorts 0..4096)
  unsigned short* Bs = lds + 4096;    // phase1 B: 256x64  (shorts 4096..20480)
  unsigned short* zs = lds;           // phase2 z: 64x128  (shorts 0..8192)
  unsigned short* Ws = lds + 8192;    // phase2 W: 128x128 (shorts 8192..24576)

  const int tid = threadIdx.x;
  const int lane = tid & 63;
  const int wave = tid >> 6;
  const int m0 = blockIdx.x * 64;
  const int lm = lane & 15, lq = lane >> 4;
  const int K = 1024;

  // ---- phase 1 staging pointers (A: 512 chunks = 2/thr; B: 2048 = 8/thr) ----
  const unsigned short* agp[2];
  const unsigned short* bgp[8];
#pragma unroll
  for (int r = 0; r < 2; ++r) {
    int c = tid + 256 * r;
    int row = c >> 3, q = (c & 7) ^ (row & 7);
    agp[r] = A + (size_t)(m0 + row) * K + q * 8;
  }
#pragma unroll
  for (int r = 0; r < 8; ++r) {
    int c = tid + 256 * r;
    int row = c >> 3, q = (c & 7) ^ (row & 7);
    bgp[r] = BT + (size_t)row * K + q * 8;
  }
  const int sw = lm & 7;

  f32x4 acc[16] = {};

  for (int kt = 0; kt < K; kt += 64) {
#pragma unroll
    for (int r = 0; r < 2; ++r) gl_lds16(agp[r] + kt, As + (tid + 256 * r) * 8);
#pragma unroll
    for (int r = 0; r < 8; ++r) gl_lds16(bgp[r] + kt, Bs + (tid + 256 * r) * 8);
    __syncthreads();

#pragma unroll
    for (int s = 0; s < 2; ++s) {
      const int so = ((s << 2) | lq) ^ sw;
      bf16x8 af = *reinterpret_cast<const bf16x8*>(As + (wave * 16 + lm) * 64 + so * 8);
#pragma unroll
      for (int j = 0; j < 16; ++j) {
        bf16x8 b = *reinterpret_cast<const bf16x8*>(Bs + (j * 16 + lm) * 64 + so * 8);
        acc[j] = __builtin_amdgcn_mfma_f32_16x16x32_bf16(af, b, acc[j], 0, 0, 0);
      }
    }
    __syncthreads();
  }
  // trailing sync above guarantees all phase-1 LDS reads are done -> zs reuse ok

  // ---- epilogue-1: z -> LDS (swizzled), kl -> out ----
  float kl[4] = {0.f, 0.f, 0.f, 0.f};
#pragma unroll
  for (int j = 0; j < 8; ++j) {
    int dim = j * 16 + lm;
    float bm = bmu[dim], bl = bls[dim];
    int chunk = dim >> 3;          // 0..15
#pragma unroll
    for (int r = 0; r < 4; ++r) {
      int lr = wave * 16 + lq * 4 + r;            // local row 0..63
      float mu = acc[j][r] + bm;
      float ls = acc[j + 8][r] + bl;
      float e = eps[(size_t)(m0 + lr) * 128 + dim];
      float zz = fmaf(__expf(ls), e, mu);
      int slot = chunk ^ (lr & 15);
      zs[lr * 128 + slot * 8 + (dim & 7)] = f32_to_bf16(zz);
      kl[r] += 0.5f * (__expf(2.f * ls) + mu * mu - 2.f * ls - 1.f);
    }
  }
#pragma unroll
  for (int off = 1; off < 16; off <<= 1)
#pragma unroll
    for (int r = 0; r < 4; ++r) kl[r] += __shfl_xor(kl[r], off, 64);
  if (lm == 0) {
#pragma unroll
    for (int r = 0; r < 4; ++r)
      out[m0 + wave * 16 + lq * 4 + r] = -kl[r];
  }

  // ---- phase 2: hd = relu(z @ Wd1 + bd1), 8 col-chunks of 128 ----
  // Ws staging: 2048 chunks (8/thr); row = c>>4 (128 rows of 128 K),
  // slot c&15 holds global chunk (c&15)^(row&15)
  int wrow[8], wq[8];
#pragma unroll
  for (int r = 0; r < 8; ++r) {
    int c = tid + 256 * r;
    wrow[r] = c >> 4;
    wq[r] = (c & 15) ^ (wrow[r] & 15);
  }

  for (int cc = 0; cc < 8; ++cc) {
#pragma unroll
    for (int r = 0; r < 8; ++r)
      gl_lds16(WD1 + (size_t)(cc * 128 + wrow[r]) * 128 + wq[r] * 8,
               Ws + (tid + 256 * r) * 8);
    __syncthreads();   // zs writes (first iter) + Ws staging complete

    f32x4 acc2[4][2] = {};
#pragma unroll
    for (int s = 0; s < 4; ++s) {
      const int c = (s << 2) | lq;         // k-chunk 0..15
      const int so = c ^ lm;               // row-swizzled slot
      bf16x8 af[4];
#pragma unroll
      for (int it = 0; it < 4; ++it)
        af[it] = *reinterpret_cast<const bf16x8*>(zs + (it * 16 + lm) * 128 + so * 8);
#pragma unroll
      for (int jt = 0; jt < 2; ++jt) {
        bf16x8 b = *reinterpret_cast<const bf16x8*>(
            Ws + (wave * 32 + jt * 16 + lm) * 128 + so * 8);
#pragma unroll
        for (int it = 0; it < 4; ++it)
          acc2[it][jt] = __builtin_amdgcn_mfma_f32_16x16x32_bf16(af[it], b, acc2[it][jt], 0, 0, 0);
      }
    }
    __syncthreads();   // Ws reads done before next chunk's staging

#pragma unroll
    for (int jt = 0; jt < 2; ++jt) {
      int col = cc * 128 + wave * 32 + jt * 16 + lm;
      float bias = bd1[col];
#pragma unroll
      for (int it = 0; it < 4; ++it)
#pragma unroll
        for (int r = 0; r < 4; ++r) {
          int row = m0 + it * 16 + lq * 4 + r;
          float v = acc2[it][jt][r] + bias;
          v = fmaxf(v, 0.f);
          hd[(size_t)row * 1024 + col] = f32_to_bf16(v);
        }
    }
  }
}

extern "C" void kernel_launch(void* const* d_in, const int* in_sizes, int n_in,
                              void* d_out, int out_size, void* d_ws, size_t ws_size,
                              hipStream_t stream) {
  const float* x   = (const float*)d_in[0];
  const float* eps = (const float*)d_in[1];
  const float* We1 = (const float*)d_in[2];
  const float* be1 = (const float*)d_in[3];
  const float* Wmu = (const float*)d_in[4];
  const float* bmu = (const float*)d_in[5];
  const float* Wls = (const float*)d_in[6];
  const float* bls = (const float*)d_in[7];
  const float* Wd1 = (const float*)d_in[8];
  const float* bd1 = (const float*)d_in[9];
  const float* Wd2 = (const float*)d_in[10];
  const float* bd2 = (const float*)d_in[11];
  float* out = (float*)d_out;

  const int B = 32768, D = 1024, H = 1024, L = 128;

  char* ws = (char*)d_ws;
  size_t off = 0;
  auto alloc = [&](size_t bytes) {
    void* p = ws + off;
    off += (bytes + 255) & ~(size_t)255;
    return p;
  };
  unsigned short* xbf  = (unsigned short*)alloc((size_t)B * D * 2);   // 64 MB
  unsigned short* w1t  = (unsigned short*)alloc((size_t)H * D * 2);   // 2 MB  [H][D]
  unsigned short* w2t  = (unsigned short*)alloc((size_t)256 * H * 2); // 0.5MB [256][H]
  unsigned short* wd1t = (unsigned short*)alloc((size_t)H * L * 2);   // .25MB [H][L]
  unsigned short* wd2t = (unsigned short*)alloc((size_t)D * H * 2);   // 2 MB  [D][H]
  unsigned short* h    = (unsigned short*)alloc((size_t)B * H * 2);   // 64 MB
  unsigned short* hd   = h;  // phase-2 writes the same rows the block read in phase 1

  // prep: transposes (blocks 0..2432) + x cast (blocks 2432..4480)
  TransJob j0{We1, w1t, D, H, 1024};
  TransJob j1{Wmu, w2t, H, L, 1152};
  TransJob j2{Wls, w2t + 128 * H, H, L, 1280};
  TransJob j3{Wd1, wd1t, L, H, 1408};
  TransJob j4{Wd2, wd2t, H, D, 2432};
  prep_k<<<4480, dim3(32, 8), 0, stream>>>(j0, j1, j2, j3, j4, x, xbf, B * D / 4);

  // GEMM1: h = relu(x @ We1 + be1)
  gemm_bt<0><<<8 * 256, 256, 0, stream>>>(
      xbf, w1t, 8, H, D, be1, h, nullptr, nullptr);
  // encoder heads + z/kl + decoder layer 1 (writes hd and out[b] = -kl[b])
  gemm23_zkl<<<B / 64, 256, 0, stream>>>(h, w2t, wd1t, bmu, bls, bd1, eps, hd, out);
  // GEMM4: bernoulli log-likelihood accumulated into out
  gemm_bt<2><<<8 * 256, 256, 0, stream>>>(
      hd, wd2t, 8, D, H, bd2, nullptr, out, xbf);

  (void)in_sizes; (void)n_in; (void)out_size; (void)ws_size;
}

// Round 8
// 473.285 us; speedup vs baseline: 1.0237x; 1.0237x over previous
//
#include <hip/hip_runtime.h>
#include <cstdint>
#include <cstddef>

// VAE forward, fused bf16-MFMA pipeline.
// Sizes fixed: B=32768, INPUT=1024, HIDDEN=1024, LATENT=128.
//
// R8: big GEMMs use BK=32 + explicit 2-buffer LDS pipeline, ONE barrier per
//     iter, ordered stage(it+1)->compute(it)->barrier. The compiler's
//     mandatory vmcnt(0) before s_barrier then drains loads issued a full
//     compute-phase earlier (hidden), instead of loads issued immediately
//     before the barrier (exposed) as in R4-R7. Total LDS stays 32 KB
//     (2x(8+8)KB), so occupancy (5 blocks/CU) is preserved -- R5 taught us
//     occupancy dominates per-iter amortization in this latency-bound regime.
// R7 (kept): gemm23_zkl fuses encoder heads + z/kl + decoder layer 1.
// R6 (kept): 128x128 block tile for big GEMMs.
// R5 (kept): fused prep kernel (5 transposes + x cast).
// R3 (kept): XCD-pinned 1D grid decode (FETCH 298->90MB).
// R2 (kept): XOR-swizzled staging (LDS bank conflicts -> 0).

typedef __bf16 bf16x8 __attribute__((ext_vector_type(8)));
typedef float f32x4 __attribute__((ext_vector_type(4)));

__device__ __forceinline__ unsigned short f32_to_bf16(float f) {
  unsigned int u = __float_as_uint(f);
  u += 0x7fffu + ((u >> 16) & 1u);   // round-to-nearest-even (finite values)
  return (unsigned short)(u >> 16);
}

// ------------- fused prep: 5 transposes + x-cast in one kernel -------------
struct TransJob { const float* in; unsigned short* out; int K, N, blkEnd; };

__global__ void prep_k(TransJob j0, TransJob j1, TransJob j2, TransJob j3,
                       TransJob j4, const float* __restrict__ x,
                       unsigned short* __restrict__ xbf, int n4) {
  int bid = blockIdx.x;
  int tid = threadIdx.y * 32 + threadIdx.x;
  if (bid >= 2432) {
    int base = (bid - 2432) * 256 + tid;
    int stride = 2048 * 256;
#pragma unroll
    for (int it = 0; it < 16; ++it) {
      int i = base + it * stride;
      float4 v = reinterpret_cast<const float4*>(x)[i];
      ushort4 o = make_ushort4(f32_to_bf16(v.x), f32_to_bf16(v.y),
                               f32_to_bf16(v.z), f32_to_bf16(v.w));
      reinterpret_cast<ushort4*>(xbf)[i] = o;
    }
    return;
  }
  __shared__ float tile[32][33];
  TransJob j; int base;
  if (bid < j0.blkEnd)      { j = j0; base = 0; }
  else if (bid < j1.blkEnd) { j = j1; base = j0.blkEnd; }
  else if (bid < j2.blkEnd) { j = j2; base = j1.blkEnd; }
  else if (bid < j3.blkEnd) { j = j3; base = j2.blkEnd; }
  else                      { j = j4; base = j3.blkEnd; }
  int local = bid - base;
  int gxN = j.N >> 5;
  int n0 = (local % gxN) * 32, k0 = (local / gxN) * 32;
  int tx = threadIdx.x, ty = threadIdx.y;  // block is 32x8
#pragma unroll
  for (int r = 0; r < 32; r += 8)
    tile[ty + r][tx] = j.in[(size_t)(k0 + ty + r) * j.N + n0 + tx];
  __syncthreads();
#pragma unroll
  for (int r = 0; r < 32; r += 8)
    j.out[(size_t)(n0 + ty + r) * j.K + k0 + tx] = f32_to_bf16(tile[tx][ty + r]);
}

// async global->LDS, 16B per lane; LDS dest must be contiguous in lane order
__device__ __forceinline__ void gl_lds16(const unsigned short* g, unsigned short* l) {
  __builtin_amdgcn_global_load_lds(
      (__attribute__((address_space(1))) void*)g,
      (__attribute__((address_space(3))) void*)l, 16, 0, 0);
}

// ---------------- GEMM: C = A[M][K] @ BT[N][K]^T + bias ----------------
// 128x128 tile, BK=32, explicit double-buffered LDS, one barrier/iter.
// 1D grid, XCD-pinned decode. EPI 0: relu->bf16. EPI 2: bernoulli LL rowsum atomicAdd.
template <int EPI>
__global__ __launch_bounds__(256) void gemm_bt(
    const unsigned short* __restrict__ A, const unsigned short* __restrict__ BT,
    int gx, int N, int K,
    const float* __restrict__ bias0,
    unsigned short* __restrict__ outb, float* __restrict__ outf,
    const unsigned short* __restrict__ xbf) {
  __shared__ __align__(16) unsigned short As[2][128 * 32];   // 2 x 8 KB
  __shared__ __align__(16) unsigned short Bs[2][128 * 32];   // 2 x 8 KB

  const int tid = threadIdx.x;
  const int lane = tid & 63;
  const int wave = tid >> 6;
  const int wr = wave >> 1, wc = wave & 1;   // 64x64 quadrant
  const int bid = blockIdx.x;
  const int xcd = bid & 7;
  const int t8 = bid >> 3;
  const int m0 = (xcd + 8 * (t8 / gx)) * 128;
  const int n0 = (t8 % gx) * 128;
  const int lm = lane & 15, lq = lane >> 4;

  // staging: 512 16B-chunks per tile -> 2 per thread; chunk c: row=c>>2,
  // LDS slot c&3 holds global chunk (c&3)^((row>>1)&3)   (R2 swizzle)
  const int c0 = tid, c1 = tid + 256;
  const int row0 = c0 >> 2, q0 = (c0 & 3) ^ ((row0 >> 1) & 3);
  const int row1 = c1 >> 2, q1 = (c1 & 3) ^ ((row1 >> 1) & 3);
  const unsigned short* agp0 = A + (size_t)(m0 + row0) * K + q0 * 8;
  const unsigned short* agp1 = A + (size_t)(m0 + row1) * K + q1 * 8;
  const unsigned short* bgp0 = BT + (size_t)(n0 + row0) * K + q0 * 8;
  const unsigned short* bgp1 = BT + (size_t)(n0 + row1) * K + q1 * 8;

  // read-side swizzle: fragment chunk lq lives at slot lq ^ ((lm>>1)&3)
  const int so = (lq ^ ((lm >> 1) & 3)) * 8;

  f32x4 acc[4][4] = {};
  const int nIter = K >> 5;

  // prologue: stage iter 0 into buffer 0 (drain exposed once)
  gl_lds16(agp0, As[0] + c0 * 8);
  gl_lds16(agp1, As[0] + c1 * 8);
  gl_lds16(bgp0, Bs[0] + c0 * 8);
  gl_lds16(bgp1, Bs[0] + c1 * 8);
  __syncthreads();

  for (int it = 0; it < nIter; ++it) {
    const int p = it & 1;
    // prefetch iter it+1 into the other buffer (its reads finished at the
    // barrier ending iter it-1); the vmcnt(0) drain at this iter's barrier
    // is then hidden behind the compute phase below.
    if (it + 1 < nIter) {
      const int off = (it + 1) << 5;
      gl_lds16(agp0 + off, As[1 - p] + c0 * 8);
      gl_lds16(agp1 + off, As[1 - p] + c1 * 8);
      gl_lds16(bgp0 + off, Bs[1 - p] + c0 * 8);
      gl_lds16(bgp1 + off, Bs[1 - p] + c1 * 8);
    }

    bf16x8 af[4], bfr[4];
#pragma unroll
    for (int i = 0; i < 4; ++i)
      af[i] = *reinterpret_cast<const bf16x8*>(As[p] + (wr * 64 + i * 16 + lm) * 32 + so);
#pragma unroll
    for (int j = 0; j < 4; ++j)
      bfr[j] = *reinterpret_cast<const bf16x8*>(Bs[p] + (wc * 64 + j * 16 + lm) * 32 + so);
#pragma unroll
    for (int i = 0; i < 4; ++i)
#pragma unroll
      for (int j = 0; j < 4; ++j)
        acc[i][j] = __builtin_amdgcn_mfma_f32_16x16x32_bf16(af[i], bfr[j], acc[i][j], 0, 0, 0);
    __syncthreads();
  }

  if (EPI == 0) {
#pragma unroll
    for (int i = 0; i < 4; ++i)
#pragma unroll
      for (int j = 0; j < 4; ++j) {
        int col = n0 + wc * 64 + j * 16 + lm;
        float bias = bias0[col];
#pragma unroll
        for (int r = 0; r < 4; ++r) {
          int row = m0 + wr * 64 + i * 16 + lq * 4 + r;
          float v = acc[i][j][r] + bias;
          v = fmaxf(v, 0.f);
          outb[(size_t)row * N + col] = f32_to_bf16(v);
        }
      }
  } else {
#pragma unroll
    for (int i = 0; i < 4; ++i) {
      float rs[4] = {0.f, 0.f, 0.f, 0.f};
#pragma unroll
      for (int j = 0; j < 4; ++j) {
        int col = n0 + wc * 64 + j * 16 + lm;
        float bias = bias0[col];
#pragma unroll
        for (int r = 0; r < 4; ++r) {
          int row = m0 + wr * 64 + i * 16 + lq * 4 + r;
          float l = acc[i][j][r] + bias;
          unsigned short xb = xbf[(size_t)row * N + col];  // 0x0000 or 0x3F80
          float t = xb ? -l : l;
          float sp = fmaxf(t, 0.f) + __logf(1.f + __expf(-fabsf(t)));
          rs[r] -= sp;
        }
      }
#pragma unroll
      for (int off = 1; off < 16; off <<= 1)
#pragma unroll
        for (int r = 0; r < 4; ++r) rs[r] += __shfl_xor(rs[r], off, 64);
      if (lm == 0) {
#pragma unroll
        for (int r = 0; r < 4; ++r)
          atomicAdd(&outf[m0 + wr * 64 + i * 16 + lq * 4 + r], rs[r]);
      }
    }
  }
}

// -------- gemm23_zkl: encoder heads + z/kl + decoder layer 1, one kernel --------
// Phase 1: 64x256 tile (4 waves x 16 rows x 256 cols), BK=64, K=1024:
//   S2 = h @ w2t^T; acc[j]: mu at n-tile j (j<8), ls at j+8 (same lane).
// Epilogue-1: z = mu+exp(ls)*eps -> LDS zs[64][128] (8-elem chunks XOR-swizzled
//   by row&15); kl rowsum -> out[b] = -kl[b].
// Phase 2: hd = relu(z @ Wd1 + bd1) over 8 col-chunks of wd1t.
__global__ __launch_bounds__(256) void gemm23_zkl(
    const unsigned short* __restrict__ A,     // h [B][1024]
    const unsigned short* __restrict__ BT,    // w2t [256][1024]
    const unsigned short* __restrict__ WD1,   // wd1t [1024][128]
    const float* __restrict__ bmu, const float* __restrict__ bls,
    const float* __restrict__ bd1,
    const float* __restrict__ eps,            // [B][128]
    unsigned short* __restrict__ hd,          // [B][1024] (may alias A: same rows)
    float* __restrict__ out) {
  __shared__ __align__(16) unsigned short lds[24576];  // 48 KB
  unsigned short* As = lds;           // phase1 A: 64x64
  unsigned short* Bs = lds + 4096;    // phase1 B: 256x64
  unsigned short* zs = lds;           // phase2 z: 64x128
  unsigned short* Ws = lds + 8192;    // phase2 W: 128x128

  const int tid = threadIdx.x;
  const int lane = tid & 63;
  const int wave = tid >> 6;
  const int m0 = blockIdx.x * 64;
  const int lm = lane & 15, lq = lane >> 4;
  const int K = 1024;

  const unsigned short* agp[2];
  const unsigned short* bgp[8];
#pragma unroll
  for (int r = 0; r < 2; ++r) {
    int c = tid + 256 * r;
    int row = c >> 3, q = (c & 7) ^ (row & 7);
    agp[r] = A + (size_t)(m0 + row) * K + q * 8;
  }
#pragma unroll
  for (int r = 0; r < 8; ++r) {
    int c = tid + 256 * r;
    int row = c >> 3, q = (c & 7) ^ (row & 7);
    bgp[r] = BT + (size_t)row * K + q * 8;
  }
  const int sw = lm & 7;

  f32x4 acc[16] = {};

  for (int kt = 0; kt < K; kt += 64) {
#pragma unroll
    for (int r = 0; r < 2; ++r) gl_lds16(agp[r] + kt, As + (tid + 256 * r) * 8);
#pragma unroll
    for (int r = 0; r < 8; ++r) gl_lds16(bgp[r] + kt, Bs + (tid + 256 * r) * 8);
    __syncthreads();

#pragma unroll
    for (int s = 0; s < 2; ++s) {
      const int so = ((s << 2) | lq) ^ sw;
      bf16x8 af = *reinterpret_cast<const bf16x8*>(As + (wave * 16 + lm) * 64 + so * 8);
#pragma unroll
      for (int j = 0; j < 16; ++j) {
        bf16x8 b = *reinterpret_cast<const bf16x8*>(Bs + (j * 16 + lm) * 64 + so * 8);
        acc[j] = __builtin_amdgcn_mfma_f32_16x16x32_bf16(af, b, acc[j], 0, 0, 0);
      }
    }
    __syncthreads();
  }

  // ---- epilogue-1: z -> LDS (swizzled), kl -> out ----
  float kl[4] = {0.f, 0.f, 0.f, 0.f};
#pragma unroll
  for (int j = 0; j < 8; ++j) {
    int dim = j * 16 + lm;
    float bm = bmu[dim], bl = bls[dim];
    int chunk = dim >> 3;          // 0..15
#pragma unroll
    for (int r = 0; r < 4; ++r) {
      int lr = wave * 16 + lq * 4 + r;            // local row 0..63
      float mu = acc[j][r] + bm;
      float ls = acc[j + 8][r] + bl;
      float e = eps[(size_t)(m0 + lr) * 128 + dim];
      float zz = fmaf(__expf(ls), e, mu);
      int slot = chunk ^ (lr & 15);
      zs[lr * 128 + slot * 8 + (dim & 7)] = f32_to_bf16(zz);
      kl[r] += 0.5f * (__expf(2.f * ls) + mu * mu - 2.f * ls - 1.f);
    }
  }
#pragma unroll
  for (int off = 1; off < 16; off <<= 1)
#pragma unroll
    for (int r = 0; r < 4; ++r) kl[r] += __shfl_xor(kl[r], off, 64);
  if (lm == 0) {
#pragma unroll
    for (int r = 0; r < 4; ++r)
      out[m0 + wave * 16 + lq * 4 + r] = -kl[r];
  }

  // ---- phase 2: hd = relu(z @ Wd1 + bd1), 8 col-chunks of 128 ----
  int wrow[8], wq[8];
#pragma unroll
  for (int r = 0; r < 8; ++r) {
    int c = tid + 256 * r;
    wrow[r] = c >> 4;
    wq[r] = (c & 15) ^ (wrow[r] & 15);
  }

  for (int cc = 0; cc < 8; ++cc) {
#pragma unroll
    for (int r = 0; r < 8; ++r)
      gl_lds16(WD1 + (size_t)(cc * 128 + wrow[r]) * 128 + wq[r] * 8,
               Ws + (tid + 256 * r) * 8);
    __syncthreads();   // zs writes (first iter) + Ws staging complete

    f32x4 acc2[4][2] = {};
#pragma unroll
    for (int s = 0; s < 4; ++s) {
      const int c = (s << 2) | lq;         // k-chunk 0..15
      const int so = c ^ lm;               // row-swizzled slot
      bf16x8 af[4];
#pragma unroll
      for (int it = 0; it < 4; ++it)
        af[it] = *reinterpret_cast<const bf16x8*>(zs + (it * 16 + lm) * 128 + so * 8);
#pragma unroll
      for (int jt = 0; jt < 2; ++jt) {
        bf16x8 b = *reinterpret_cast<const bf16x8*>(
            Ws + (wave * 32 + jt * 16 + lm) * 128 + so * 8);
#pragma unroll
        for (int it = 0; it < 4; ++it)
          acc2[it][jt] = __builtin_amdgcn_mfma_f32_16x16x32_bf16(af[it], b, acc2[it][jt], 0, 0, 0);
      }
    }
    __syncthreads();   // Ws reads done before next chunk's staging

#pragma unroll
    for (int jt = 0; jt < 2; ++jt) {
      int col = cc * 128 + wave * 32 + jt * 16 + lm;
      float bias = bd1[col];
#pragma unroll
      for (int it = 0; it < 4; ++it)
#pragma unroll
        for (int r = 0; r < 4; ++r) {
          int row = m0 + it * 16 + lq * 4 + r;
          float v = acc2[it][jt][r] + bias;
          v = fmaxf(v, 0.f);
          hd[(size_t)row * 1024 + col] = f32_to_bf16(v);
        }
    }
  }
}

extern "C" void kernel_launch(void* const* d_in, const int* in_sizes, int n_in,
                              void* d_out, int out_size, void* d_ws, size_t ws_size,
                              hipStream_t stream) {
  const float* x   = (const float*)d_in[0];
  const float* eps = (const float*)d_in[1];
  const float* We1 = (const float*)d_in[2];
  const float* be1 = (const float*)d_in[3];
  const float* Wmu = (const float*)d_in[4];
  const float* bmu = (const float*)d_in[5];
  const float* Wls = (const float*)d_in[6];
  const float* bls = (const float*)d_in[7];
  const float* Wd1 = (const float*)d_in[8];
  const float* bd1 = (const float*)d_in[9];
  const float* Wd2 = (const float*)d_in[10];
  const float* bd2 = (const float*)d_in[11];
  float* out = (float*)d_out;

  const int B = 32768, D = 1024, H = 1024, L = 128;

  char* ws = (char*)d_ws;
  size_t off = 0;
  auto alloc = [&](size_t bytes) {
    void* p = ws + off;
    off += (bytes + 255) & ~(size_t)255;
    return p;
  };
  unsigned short* xbf  = (unsigned short*)alloc((size_t)B * D * 2);   // 64 MB
  unsigned short* w1t  = (unsigned short*)alloc((size_t)H * D * 2);   // 2 MB  [H][D]
  unsigned short* w2t  = (unsigned short*)alloc((size_t)256 * H * 2); // 0.5MB [256][H]
  unsigned short* wd1t = (unsigned short*)alloc((size_t)H * L * 2);   // .25MB [H][L]
  unsigned short* wd2t = (unsigned short*)alloc((size_t)D * H * 2);   // 2 MB  [D][H]
  unsigned short* h    = (unsigned short*)alloc((size_t)B * H * 2);   // 64 MB
  unsigned short* hd   = h;  // phase-2 writes the same rows the block read in phase 1

  // prep: transposes (blocks 0..2432) + x cast (blocks 2432..4480)
  TransJob j0{We1, w1t, D, H, 1024};
  TransJob j1{Wmu, w2t, H, L, 1152};
  TransJob j2{Wls, w2t + 128 * H, H, L, 1280};
  TransJob j3{Wd1, wd1t, L, H, 1408};
  TransJob j4{Wd2, wd2t, H, D, 2432};
  prep_k<<<4480, dim3(32, 8), 0, stream>>>(j0, j1, j2, j3, j4, x, xbf, B * D / 4);

  // GEMM1: h = relu(x @ We1 + be1)
  gemm_bt<0><<<8 * 256, 256, 0, stream>>>(
      xbf, w1t, 8, H, D, be1, h, nullptr, nullptr);
  // encoder heads + z/kl + decoder layer 1 (writes hd and out[b] = -kl[b])
  gemm23_zkl<<<B / 64, 256, 0, stream>>>(h, w2t, wd1t, bmu, bls, bd1, eps, hd, out);
  // GEMM4: bernoulli log-likelihood accumulated into out
  gemm_bt<2><<<8 * 256, 256, 0, stream>>>(
      hd, wd2t, 8, D, H, bd2, nullptr, out, xbf);

  (void)in_sizes; (void)n_in; (void)out_size; (void)ws_size;
}